// Round 9
// baseline (63.828 us; speedup 1.0000x reference)
//
#include <hip/hip_runtime.h>
#include <hip/hip_bf16.h>
#include <math.h>

#define N 1024
#define TB 16

typedef __attribute__((ext_vector_type(8))) short short8;
typedef __attribute__((ext_vector_type(4))) short short4v;
typedef __attribute__((ext_vector_type(4))) float f32x4;

// PReLU via max/min: max(v,0) + a*min(v,0)
__device__ __forceinline__ float prelu(float v, float a) {
    return fmaxf(v, 0.f) + a * fminf(v, 0.f);
}

// f32 -> bf16 RNE via hardware cvt (pairs into v_cvt_pk_bf16_f32)
__device__ __forceinline__ short f2bf(float f) {
    return (short)__bfloat16_as_ushort(__float2bfloat16(f));
}

__global__ __launch_bounds__(256, 8) void precond_mfma(
    const float* __restrict__ xg, const int* __restrict__ maskg,
    const float* __restrict__ w1, const float* __restrict__ b1, const float* __restrict__ a1p,
    const float* __restrict__ w2, const float* __restrict__ b2, const float* __restrict__ a2p,
    const float* __restrict__ w3, const float* __restrict__ b3, const float* __restrict__ a3p,
    const float* __restrict__ w4, const float* __restrict__ b4p,
    float* __restrict__ out)
{
    const int tid = threadIdx.x;
    const int bz  = blockIdx.z;
    const int ty0 = blockIdx.y * TB, tx0 = blockIdx.x * TB;

    // ---- Early exit: tile entirely above the diagonal -> all zeros ----
    if (blockIdx.y < blockIdx.x) {
        int ty = tid >> 4, tx = tid & 15;
        out[((size_t)bz * N + ty0 + ty) * N + tx0 + tx] = 0.f;
        return;
    }

    __shared__ __align__(16) short h1s[324 * 8];    // [pos 18x18][8ch] bf16, 16B/pos
    __shared__ __align__(16) short h2lo[289 * 8];   // [pos 17x17][ch 0-7]  bf16
    __shared__ __align__(16) short h2hi[289 * 8];   // [pos 17x17][ch 8-15] bf16
    __shared__ __align__(16) unsigned RMv[20];      // layer-1 mask row bitmaps (18 rows, bit c)
    __shared__ unsigned short m2su[289];            // spread mask at h2 positions

    const int lane = tid & 63, wid = tid >> 6;
    const int c16 = lane & 15, g = lane >> 4;

    const float a1 = a1p[0], a2 = a2p[0], a3 = a3p[0];
    const float b4 = b4p[0];
    const bool leftEdge  = (tx0 == 0);
    const bool rightEdge = (tx0 == N - TB);

    // --- per-lane weight fragments direct from global (L2-hot; VMEM pipe) ---
    // L2 A-frag: lane(c16,g) holds W2[oc=c16][k=g*8+j], k=khkw*8+ic -> w2[o*32 + i*4 + khkw]
    short8 a2f, a3f0, a3f1;
#pragma unroll
    for (int j = 0; j < 8; ++j) a2f[j] = f2bf(w2[c16 * 32 + j * 4 + g]);
    // L3 A-frags: k = khkw*16 + ic; a3f0: k=g*8..+7, a3f1: k=32+g*8..+7; oc>=8 -> 0
#pragma unroll
    for (int j = 0; j < 8; ++j) {
        int k0 = g * 8 + j, k1 = 32 + g * 8 + j;
        a3f0[j] = (c16 < 8) ? f2bf(w3[c16 * 64 + (k0 & 15) * 4 + (k0 >> 4)]) : (short)0;
        a3f1[j] = (c16 < 8) ? f2bf(w3[c16 * 64 + (k1 & 15) * 4 + (k1 >> 4)]) : (short)0;
    }
    f32x4 bias2, bias3;
    float w4r[4];
#pragma unroll
    for (int r = 0; r < 4; ++r) {
        bias2[r] = b2[g * 4 + r];
        bias3[r] = (g < 2) ? b3[g * 4 + r] : 0.f;
        w4r[r]   = (g < 2) ? w4[g * 4 + r] : 0.f;
    }

    // --- Phase A: h1 + ballot row-bitmasks. 32-padded layout: slot = r*32 + c. ---
    // Each wave-iter covers exactly 2 rows (64 lanes / 32 cols); one __ballot gives both
    // row bitmaps; lane 0 stores them with a single b64 write.
    for (int p4 = tid; p4 < 18 * 32; p4 += 256) {
        int r = p4 >> 5, c = p4 & 31;
        int gy = ty0 - 1 + r, gx = tx0 - 1 + c;
        bool mb = false;
        float xv = 0.f;
        if (c < 18 && (unsigned)gy < N && (unsigned)gx < N) {
            size_t idx = ((size_t)bz * N + gy) * N + gx;
            mb = (maskg[idx] > 0);
            xv = xg[idx];
        }
        unsigned long long bal = __ballot(mb);
        if (lane == 0) {
            // rows covered by this wave-iter: R = p4>>5 (even), R+1
            *(uint2*)&RMv[p4 >> 5] = make_uint2((unsigned)bal, (unsigned)(bal >> 32));
        }
        short8 hv;
#pragma unroll
        for (int ch = 0; ch < 8; ++ch) hv[ch] = f2bf(prelu(fmaf(xv, w1[ch], b1[ch]), a1));
        if (!mb) hv = (short8)0;
        if (c < 18) *(short8*)&h1s[(r * 18 + c) * 8] = hv;
    }
    __syncthreads();

    // --- Phase B: h2 at 17x17 positions via MFMA (K=32: 4 khkw x 8 ic) ---
    // 19 groups of 16 positions: wave w handles {w, w+4, w+8, w+12} and (w<3) {16+w}.
    {
        const int kh = g >> 1, kw = g & 1;
#pragma unroll
        for (int k = 0; k < 5; ++k) {
            if (k == 4 && wid == 3) break;            // wave-uniform
            const int grp = (k < 4) ? (wid + 4 * k) : (16 + wid);
            int p = grp * 16 + c16;
            bool valid = p < 289;
            int pc = valid ? p : 288;
            int dy2 = pc / 17, dx2 = pc - dy2 * 17;

            short8 bf = *(const short8*)&h1s[((dy2 + kh) * 18 + dx2 + kw) * 8];
            f32x4 acc = __builtin_amdgcn_mfma_f32_16x16x32_bf16(a2f, bf, bias2, 0, 0, 0);

            // spread mask from row bitmaps: 2 broadcast u32 reads + shift
            unsigned both = RMv[dy2] | RMv[dy2 + 1];
            unsigned m2 = (both >> dx2) & 3u;
            if ((leftEdge && dx2 == 0) || (rightEdge && dx2 == 16)) m2 = 0;

            short4v hv;
#pragma unroll
            for (int r = 0; r < 4; ++r) hv[r] = f2bf(prelu(acc[r], a2));
            if (m2 == 0) { hv[0] = 0; hv[1] = 0; hv[2] = 0; hv[3] = 0; }

            if (valid) {
                short* dst = (g & 2) ? (short*)h2hi : (short*)h2lo;
                *(short4v*)&dst[pc * 8 + (g & 1) * 4] = hv;
                if (g == 0) m2su[pc] = (unsigned short)(m2 != 0);
            }
        }
    }
    __syncthreads();

    // --- Phase C: h3 via 2 chained MFMAs (K=64) + layer4 + epilogue ---
    {
        const int kw = g >> 1, ic8 = g & 1;
        const short* h2sel = ic8 ? (const short*)h2hi : (const short*)h2lo;
        const int base = wid * 4;

        // row-fragment reuse: rows base..base+4, read each once
        short8 bfp = *(const short8*)&h2sel[(base * 17 + c16 + kw) * 8];
#pragma unroll
        for (int j = 0; j < 4; ++j) {
            const int G = base + j;
            short8 bfn = *(const short8*)&h2sel[((G + 1) * 17 + c16 + kw) * 8];
            f32x4 acc = __builtin_amdgcn_mfma_f32_16x16x32_bf16(a3f0, bfp, bias3, 0, 0, 0);
            acc = __builtin_amdgcn_mfma_f32_16x16x32_bf16(a3f1, bfn, acc, 0, 0, 0);
            bfp = bfn;

            float partial = 0.f;
#pragma unroll
            for (int r = 0; r < 4; ++r) partial = fmaf(prelu(acc[r], a3), w4r[r], partial);
            // oc live only in g=0,1 (g>=2 partials are exactly 0): one xor-16 suffices
            partial += __shfl_xor(partial, 16, 64);

            if (g == 0) {
                int mb = G * 17 + c16;
                unsigned m3 = (unsigned)(m2su[mb] | m2su[mb + 1] |
                                         m2su[mb + 17] | m2su[mb + 18]);
                float outv = m3 ? (partial + b4) : 0.f;
                int y = ty0 + G, x = tx0 + c16;
                if (y < x) {
                    outv = 0.f;
                } else if (y == x && m3) {
                    outv = fmaxf(outv, 0.f) + log1pf(expf(-fabsf(outv)));
                }
                out[((size_t)bz * N + y) * N + x] = outv;
            }
        }
    }
}

extern "C" void kernel_launch(void* const* d_in, const int* in_sizes, int n_in,
                              void* d_out, int out_size, void* d_ws, size_t ws_size,
                              hipStream_t stream) {
    const float* x    = (const float*)d_in[0];
    const int*   mask = (const int*)  d_in[1];
    const float* w1   = (const float*)d_in[2];
    const float* b1   = (const float*)d_in[3];
    const float* a1   = (const float*)d_in[4];
    const float* w2   = (const float*)d_in[5];
    const float* b2   = (const float*)d_in[6];
    const float* a2   = (const float*)d_in[7];
    const float* w3   = (const float*)d_in[8];
    const float* b3   = (const float*)d_in[9];
    const float* a3   = (const float*)d_in[10];
    const float* w4   = (const float*)d_in[11];
    const float* b4   = (const float*)d_in[12];
    float* out = (float*)d_out;

    dim3 grid(N / TB, N / TB, 2);
    precond_mfma<<<grid, 256, 0, stream>>>(x, mask, w1, b1, a1, w2, b2, a2,
                                           w3, b3, a3, w4, b4, out);
}

// Round 10
// 32.517 us; speedup vs baseline: 1.9629x; 1.9629x over previous
//
#include <hip/hip_runtime.h>
#include <hip/hip_bf16.h>
#include <math.h>

#define N 1024
#define TB 16

typedef __attribute__((ext_vector_type(8))) short short8;
typedef __attribute__((ext_vector_type(4))) short short4v;
typedef __attribute__((ext_vector_type(4))) float f32x4;

// PReLU via max/min: max(v,0) + a*min(v,0)
__device__ __forceinline__ float prelu(float v, float a) {
    return fmaxf(v, 0.f) + a * fminf(v, 0.f);
}

// f32 -> bf16 RNE via hardware cvt (pairs into v_cvt_pk_bf16_f32)
__device__ __forceinline__ short f2bf(float f) {
    return (short)__bfloat16_as_ushort(__float2bfloat16(f));
}

__global__ __launch_bounds__(256, 8) void precond_mfma(
    const float* __restrict__ xg, const int* __restrict__ maskg,
    const float* __restrict__ w1, const float* __restrict__ b1, const float* __restrict__ a1p,
    const float* __restrict__ w2, const float* __restrict__ b2, const float* __restrict__ a2p,
    const float* __restrict__ w3, const float* __restrict__ b3, const float* __restrict__ a3p,
    const float* __restrict__ w4, const float* __restrict__ b4p,
    float* __restrict__ out)
{
    const int tid = threadIdx.x;
    const int bz  = blockIdx.z;
    const int ty0 = blockIdx.y * TB, tx0 = blockIdx.x * TB;

    // ---- Early exit: tile entirely above the diagonal -> all zeros ----
    if (blockIdx.y < blockIdx.x) {
        int ty = tid >> 4, tx = tid & 15;
        out[((size_t)bz * N + ty0 + ty) * N + tx0 + tx] = 0.f;
        return;
    }

    __shared__ __align__(16) short sW2[512];        // [oc=16][k=32], k = khkw*8 + ic
    __shared__ __align__(16) short sW3[1024];       // [oc=16][k=64], k = khkw*16 + ic (oc>=8 zero)
    __shared__ __align__(16) short h1s[324 * 8];    // [pos 18x18][8ch] bf16, 16B/pos
    __shared__ __align__(16) short h2lo[289 * 8];   // [pos 17x17][ch 0-7]  bf16
    __shared__ __align__(16) short h2hi[289 * 8];   // [pos 17x17][ch 8-15] bf16
    __shared__ __align__(16) unsigned RM1[12];      // layer-1 mask, flat bitmap over 18x18 (324 bits)
    __shared__ __align__(16) unsigned M2f[10];      // spread mask, flat bitmap over 17x17 (289 bits)

    const int lane = tid & 63, wid = tid >> 6;
    const int c16 = lane & 15, g = lane >> 4;

    const float a1 = a1p[0], a2 = a2p[0], a3 = a3p[0];
    const float b4 = b4p[0];
    const bool leftEdge  = (tx0 == 0);
    const bool rightEdge = (tx0 == N - TB);

    // --- stage transposed bf16 weights (coalesced, LDS; fragments read once per wave) ---
    for (int t = tid; t < 512; t += 256) {
        int o = t >> 5, khkw = (t >> 3) & 3, i = t & 7;
        sW2[t] = f2bf(w2[((o * 8 + i) * 2 + (khkw >> 1)) * 2 + (khkw & 1)]);
    }
    for (int t = tid; t < 1024; t += 256) {
        int oc = t >> 6, k = t & 63, khkw = k >> 4, i = k & 15;
        sW3[t] = (oc < 8) ? f2bf(w3[((oc * 16 + i) * 2 + (khkw >> 1)) * 2 + (khkw & 1)]) : (short)0;
    }

    // --- Phase A: h1 (masked, PReLU'd, bf16) + ballot mask bitmap (18x18 halo) ---
    // Loop chunks are wave-contiguous: wave w at step k covers positions 256k+64w .. +63,
    // so one __ballot gives 64 flat mask bits; lane 0 stores them (uint2 = words 2c, 2c+1).
    for (int p = tid; p < 324; p += 256) {
        int dy = p / 18, dx = p - dy * 18;
        int gy = ty0 - 1 + dy, gx = tx0 - 1 + dx;
        bool mb = false;
        float xv = 0.f;
        if ((unsigned)gy < N && (unsigned)gx < N) {
            size_t idx = ((size_t)bz * N + gy) * N + gx;
            mb = (maskg[idx] > 0);
            xv = xg[idx];
        }
        unsigned long long bal = __ballot(mb);
        if (lane == 0) {
            int c = (p - lane) >> 6;    // chunk index = wid + 4k
            *(uint2*)&RM1[2 * c] = make_uint2((unsigned)bal, (unsigned)(bal >> 32));
        }
        short8 hv;
#pragma unroll
        for (int ch = 0; ch < 8; ++ch) hv[ch] = f2bf(prelu(fmaf(xv, w1[ch], b1[ch]), a1));
        if (!mb) hv = (short8)0;
        *(short8*)&h1s[p * 8] = hv;
    }
    __syncthreads();

    // --- Phase B: h2 at 17x17 positions via MFMA (K=32: 4 khkw x 8 ic) ---
    // 19 groups of 16 positions: wave w handles {w, w+4, w+8, w+12} and (w<3) {16+w}.
    {
        short8 a2f = *(const short8*)&sW2[c16 * 32 + g * 8];
        const int kh = g >> 1, kw = g & 1;
        f32x4 bias2;
#pragma unroll
        for (int r = 0; r < 4; ++r) bias2[r] = b2[g * 4 + r];

#pragma unroll
        for (int k = 0; k < 5; ++k) {
            if (k == 4 && wid == 3) break;            // wave-uniform
            const int grp = (k < 4) ? (wid + 4 * k) : (16 + wid);
            int p = grp * 16 + c16;
            bool valid = p < 289;
            int pc = valid ? p : 288;
            int dy2 = pc / 17, dx2 = pc - dy2 * 17;

            short8 bf = *(const short8*)&h1s[((dy2 + kh) * 18 + dx2 + kw) * 8];
            f32x4 acc = __builtin_amdgcn_mfma_f32_16x16x32_bf16(a2f, bf, bias2, 0, 0, 0);

            // spread mask from flat bitmap: bits q, q+1, q+18, q+19 of RM1
            int q = dy2 * 18 + dx2, w0 = q >> 5, sh = q & 31;
            unsigned long long v64 = ((unsigned long long)RM1[w0 + 1] << 32) | RM1[w0];
            unsigned long long v = v64 >> sh;
            unsigned m2 = (unsigned)((v | (v >> 1) | (v >> 18) | (v >> 19)) & 1ull);
            if ((leftEdge && dx2 == 0) || (rightEdge && dx2 == 16)) m2 = 0;
            if (!valid) m2 = 0;

            // build m2 bitmap: group's 16 bits from ballot (bits 0-15 = c16 lanes of g=0)
            unsigned long long balm = __ballot(m2 != 0);
            if (lane == 0) ((unsigned short*)M2f)[grp] = (unsigned short)(balm & 0xFFFFull);

            short4v hv;
#pragma unroll
            for (int r = 0; r < 4; ++r) hv[r] = f2bf(prelu(acc[r], a2));
            if (m2 == 0) { hv[0] = 0; hv[1] = 0; hv[2] = 0; hv[3] = 0; }

            if (valid) {
                short* dst = (g & 2) ? (short*)h2hi : (short*)h2lo;
                *(short4v*)&dst[pc * 8 + (g & 1) * 4] = hv;
            }
        }
    }
    __syncthreads();

    // --- Phase C: h3 via 2 chained MFMAs (K=64) + layer4 + epilogue ---
    {
        short8 a3f0 = *(const short8*)&sW3[c16 * 64 + g * 8];        // k 0..31  (kh=0)
        short8 a3f1 = *(const short8*)&sW3[c16 * 64 + 32 + g * 8];   // k 32..63 (kh=1)
        const int kw = g >> 1, ic8 = g & 1;
        const short* h2sel = ic8 ? (const short*)h2hi : (const short*)h2lo;
        const int base = wid * 4;
        f32x4 bias3;
        float w4r[4];
#pragma unroll
        for (int r = 0; r < 4; ++r) {
            bias3[r] = (g < 2) ? b3[g * 4 + r] : 0.f;
            w4r[r]   = (g < 2) ? w4[g * 4 + r] : 0.f;
        }

        // row-fragment reuse: rows base..base+4 read once each (5 b128 instead of 8)
        short8 bfp = *(const short8*)&h2sel[(base * 17 + c16 + kw) * 8];
#pragma unroll
        for (int j = 0; j < 4; ++j) {
            const int G = base + j;
            short8 bfn = *(const short8*)&h2sel[((G + 1) * 17 + c16 + kw) * 8];
            f32x4 acc = __builtin_amdgcn_mfma_f32_16x16x32_bf16(a3f0, bfp, bias3, 0, 0, 0);
            acc = __builtin_amdgcn_mfma_f32_16x16x32_bf16(a3f1, bfn, acc, 0, 0, 0);
            bfp = bfn;

            float partial = 0.f;
#pragma unroll
            for (int r = 0; r < 4; ++r) partial = fmaf(prelu(acc[r], a3), w4r[r], partial);
            // oc live only in g=0,1 (g>=2 partials exactly 0): one xor-16 suffices
            partial += __shfl_xor(partial, 16, 64);

            if (g == 0) {
                // m3 from m2 bitmap: bits q2, q2+1, q2+17, q2+18
                int q2 = G * 17 + c16, w2i = q2 >> 5, sh2 = q2 & 31;
                unsigned long long v64 = ((unsigned long long)M2f[w2i + 1] << 32) | M2f[w2i];
                unsigned long long v = v64 >> sh2;
                unsigned m3 = (unsigned)((v | (v >> 1) | (v >> 17) | (v >> 18)) & 1ull);

                float outv = m3 ? (partial + b4) : 0.f;
                int y = ty0 + G, x = tx0 + c16;
                if (y < x) {
                    outv = 0.f;
                } else if (y == x && m3) {
                    outv = fmaxf(outv, 0.f) + log1pf(expf(-fabsf(outv)));
                }
                out[((size_t)bz * N + y) * N + x] = outv;
            }
        }
    }
}

extern "C" void kernel_launch(void* const* d_in, const int* in_sizes, int n_in,
                              void* d_out, int out_size, void* d_ws, size_t ws_size,
                              hipStream_t stream) {
    const float* x    = (const float*)d_in[0];
    const int*   mask = (const int*)  d_in[1];
    const float* w1   = (const float*)d_in[2];
    const float* b1   = (const float*)d_in[3];
    const float* a1   = (const float*)d_in[4];
    const float* w2   = (const float*)d_in[5];
    const float* b2   = (const float*)d_in[6];
    const float* a2   = (const float*)d_in[7];
    const float* w3   = (const float*)d_in[8];
    const float* b3   = (const float*)d_in[9];
    const float* a3   = (const float*)d_in[10];
    const float* w4   = (const float*)d_in[11];
    const float* b4   = (const float*)d_in[12];
    float* out = (float*)d_out;

    dim3 grid(N / TB, N / TB, 2);
    precond_mfma<<<grid, 256, 0, stream>>>(x, mask, w1, b1, a1, w2, b2, a2,
                                           w3, b3, a3, w4, b4, out);
}

// Round 11
// 27.557 us; speedup vs baseline: 2.3162x; 1.1800x over previous
//
#include <hip/hip_runtime.h>
#include <hip/hip_bf16.h>
#include <math.h>

#define N 1024
#define TB 16

typedef __attribute__((ext_vector_type(8))) short short8;
typedef __attribute__((ext_vector_type(4))) short short4v;
typedef __attribute__((ext_vector_type(4))) float f32x4;

// PReLU via max/min: max(v,0) + a*min(v,0)
__device__ __forceinline__ float prelu(float v, float a) {
    return fmaxf(v, 0.f) + a * fminf(v, 0.f);
}

// f32 -> bf16 RNE via hardware cvt (pairs into v_cvt_pk_bf16_f32)
__device__ __forceinline__ short f2bf(float f) {
    return (short)__bfloat16_as_ushort(__float2bfloat16(f));
}

// Triangular grid: blockIdx.x enumerates only the 2080 lower-triangle tiles
// (per batch). The 2016 upper-triangle zero tiles are fused as a one-store
// prologue into the first 2016 blocks. Inner pipeline identical to R10.
__global__ __launch_bounds__(256, 8) void precond_mfma(
    const float* __restrict__ xg, const int* __restrict__ maskg,
    const float* __restrict__ w1, const float* __restrict__ b1, const float* __restrict__ a1p,
    const float* __restrict__ w2, const float* __restrict__ b2, const float* __restrict__ a2p,
    const float* __restrict__ w3, const float* __restrict__ b3, const float* __restrict__ a3p,
    const float* __restrict__ w4, const float* __restrict__ b4p,
    float* __restrict__ out)
{
    const int tid = threadIdx.x;
    const int bz  = blockIdx.z;
    const int t   = blockIdx.x;

    // ---- triangular mapping: t -> (by, bx), bx <= by ----
    int by = (int)((sqrtf(8.0f * (float)t + 1.0f) - 1.0f) * 0.5f);
    while ((by + 1) * (by + 2) / 2 <= t) ++by;
    while (by * (by + 1) / 2 > t) --by;
    const int bx = t - by * (by + 1) / 2;
    const int ty0 = by * TB, tx0 = bx * TB;

    // ---- fused zero-fill: block t (t<2016) also clears upper tile #t ----
    // strict-upper tiles (row<col): t = y(y-1)/2 + x, x < y  ->  tile (row=x, col=y)
    if (t < 2016) {
        int y = (int)((sqrtf(8.0f * (float)t + 1.0f) + 1.0f) * 0.5f);
        while (y * (y - 1) / 2 > t) --y;
        while ((y + 1) * y / 2 <= t) ++y;
        int xs = t - y * (y - 1) / 2;
        int zy = xs * TB + (tid >> 4), zx = y * TB + (tid & 15);
        out[((size_t)bz * N + zy) * N + zx] = 0.f;   // fire-and-forget
    }

    __shared__ __align__(16) short sW2[512];        // [oc=16][k=32], k = khkw*8 + ic
    __shared__ __align__(16) short sW3[1024];       // [oc=16][k=64], k = khkw*16 + ic (oc>=8 zero)
    __shared__ __align__(16) short h1s[324 * 8];    // [pos 18x18][8ch] bf16, 16B/pos
    __shared__ __align__(16) short h2lo[289 * 8];   // [pos 17x17][ch 0-7]  bf16
    __shared__ __align__(16) short h2hi[289 * 8];   // [pos 17x17][ch 8-15] bf16
    __shared__ __align__(16) unsigned RM1[12];      // layer-1 mask, flat bitmap over 18x18
    __shared__ __align__(16) unsigned M2f[10];      // spread mask, flat bitmap over 17x17

    const int lane = tid & 63, wid = tid >> 6;
    const int c16 = lane & 15, g = lane >> 4;

    const float a1 = a1p[0], a2 = a2p[0], a3 = a3p[0];
    const float b4 = b4p[0];
    const bool leftEdge  = (tx0 == 0);
    const bool rightEdge = (tx0 == N - TB);

    // --- stage transposed bf16 weights (coalesced, LDS) ---
    for (int u = tid; u < 512; u += 256) {
        int o = u >> 5, khkw = (u >> 3) & 3, i = u & 7;
        sW2[u] = f2bf(w2[((o * 8 + i) * 2 + (khkw >> 1)) * 2 + (khkw & 1)]);
    }
    for (int u = tid; u < 1024; u += 256) {
        int oc = u >> 6, k = u & 63, khkw = k >> 4, i = k & 15;
        sW3[u] = (oc < 8) ? f2bf(w3[((oc * 16 + i) * 2 + (khkw >> 1)) * 2 + (khkw & 1)]) : (short)0;
    }

    // --- Phase A: h1 (masked, PReLU'd, bf16) + ballot mask bitmap (18x18 halo) ---
    for (int p = tid; p < 324; p += 256) {
        int dy = p / 18, dx = p - dy * 18;
        int gy = ty0 - 1 + dy, gx = tx0 - 1 + dx;
        bool mb = false;
        float xv = 0.f;
        if ((unsigned)gy < N && (unsigned)gx < N) {
            size_t idx = ((size_t)bz * N + gy) * N + gx;
            mb = (maskg[idx] > 0);
            xv = xg[idx];
        }
        unsigned long long bal = __ballot(mb);
        if (lane == 0) {
            int c = (p - lane) >> 6;    // chunk index
            *(uint2*)&RM1[2 * c] = make_uint2((unsigned)bal, (unsigned)(bal >> 32));
        }
        short8 hv;
#pragma unroll
        for (int ch = 0; ch < 8; ++ch) hv[ch] = f2bf(prelu(fmaf(xv, w1[ch], b1[ch]), a1));
        if (!mb) hv = (short8)0;
        *(short8*)&h1s[p * 8] = hv;
    }
    __syncthreads();

    // --- Phase B: h2 at 17x17 positions via MFMA (K=32: 4 khkw x 8 ic) ---
    {
        short8 a2f = *(const short8*)&sW2[c16 * 32 + g * 8];
        const int kh = g >> 1, kw = g & 1;
        f32x4 bias2;
#pragma unroll
        for (int r = 0; r < 4; ++r) bias2[r] = b2[g * 4 + r];

#pragma unroll
        for (int k = 0; k < 5; ++k) {
            if (k == 4 && wid == 3) break;            // wave-uniform
            const int grp = (k < 4) ? (wid + 4 * k) : (16 + wid);
            int p = grp * 16 + c16;
            bool valid = p < 289;
            int pc = valid ? p : 288;
            int dy2 = pc / 17, dx2 = pc - dy2 * 17;

            short8 bf = *(const short8*)&h1s[((dy2 + kh) * 18 + dx2 + kw) * 8];
            f32x4 acc = __builtin_amdgcn_mfma_f32_16x16x32_bf16(a2f, bf, bias2, 0, 0, 0);

            // spread mask from flat bitmap: bits q, q+1, q+18, q+19 of RM1
            int q = dy2 * 18 + dx2, w0 = q >> 5, sh = q & 31;
            unsigned long long v64 = ((unsigned long long)RM1[w0 + 1] << 32) | RM1[w0];
            unsigned long long v = v64 >> sh;
            unsigned m2 = (unsigned)((v | (v >> 1) | (v >> 18) | (v >> 19)) & 1ull);
            if ((leftEdge && dx2 == 0) || (rightEdge && dx2 == 16)) m2 = 0;
            if (!valid) m2 = 0;

            // build m2 bitmap: group's 16 bits from ballot
            unsigned long long balm = __ballot(m2 != 0);
            if (lane == 0) ((unsigned short*)M2f)[grp] = (unsigned short)(balm & 0xFFFFull);

            short4v hv;
#pragma unroll
            for (int r = 0; r < 4; ++r) hv[r] = f2bf(prelu(acc[r], a2));
            if (m2 == 0) { hv[0] = 0; hv[1] = 0; hv[2] = 0; hv[3] = 0; }

            if (valid) {
                short* dst = (g & 2) ? (short*)h2hi : (short*)h2lo;
                *(short4v*)&dst[pc * 8 + (g & 1) * 4] = hv;
            }
        }
    }
    __syncthreads();

    // --- Phase C: h3 via 2 chained MFMAs (K=64) + layer4 + epilogue ---
    {
        short8 a3f0 = *(const short8*)&sW3[c16 * 64 + g * 8];        // k 0..31  (kh=0)
        short8 a3f1 = *(const short8*)&sW3[c16 * 64 + 32 + g * 8];   // k 32..63 (kh=1)
        const int kw = g >> 1, ic8 = g & 1;
        const short* h2sel = ic8 ? (const short*)h2hi : (const short*)h2lo;
        const int base = wid * 4;
        f32x4 bias3;
        float w4r[4];
#pragma unroll
        for (int r = 0; r < 4; ++r) {
            bias3[r] = (g < 2) ? b3[g * 4 + r] : 0.f;
            w4r[r]   = (g < 2) ? w4[g * 4 + r] : 0.f;
        }

        // row-fragment reuse: rows base..base+4 read once each
        short8 bfp = *(const short8*)&h2sel[(base * 17 + c16 + kw) * 8];
#pragma unroll
        for (int j = 0; j < 4; ++j) {
            const int G = base + j;
            short8 bfn = *(const short8*)&h2sel[((G + 1) * 17 + c16 + kw) * 8];
            f32x4 acc = __builtin_amdgcn_mfma_f32_16x16x32_bf16(a3f0, bfp, bias3, 0, 0, 0);
            acc = __builtin_amdgcn_mfma_f32_16x16x32_bf16(a3f1, bfn, acc, 0, 0, 0);
            bfp = bfn;

            float partial = 0.f;
#pragma unroll
            for (int r = 0; r < 4; ++r) partial = fmaf(prelu(acc[r], a3), w4r[r], partial);
            partial += __shfl_xor(partial, 16, 64);   // oc live only in g=0,1

            if (g == 0) {
                // m3 from m2 bitmap: bits q2, q2+1, q2+17, q2+18
                int q2 = G * 17 + c16, w2i = q2 >> 5, sh2 = q2 & 31;
                unsigned long long v64 = ((unsigned long long)M2f[w2i + 1] << 32) | M2f[w2i];
                unsigned long long v = v64 >> sh2;
                unsigned m3 = (unsigned)((v | (v >> 1) | (v >> 17) | (v >> 18)) & 1ull);

                float outv = m3 ? (partial + b4) : 0.f;
                int y = ty0 + G, x = tx0 + c16;
                if (y < x) {
                    outv = 0.f;
                } else if (y == x && m3) {
                    outv = fmaxf(outv, 0.f) + log1pf(expf(-fabsf(outv)));
                }
                out[((size_t)bz * N + y) * N + x] = outv;
            }
        }
    }
}

extern "C" void kernel_launch(void* const* d_in, const int* in_sizes, int n_in,
                              void* d_out, int out_size, void* d_ws, size_t ws_size,
                              hipStream_t stream) {
    const float* x    = (const float*)d_in[0];
    const int*   mask = (const int*)  d_in[1];
    const float* w1   = (const float*)d_in[2];
    const float* b1   = (const float*)d_in[3];
    const float* a1   = (const float*)d_in[4];
    const float* w2   = (const float*)d_in[5];
    const float* b2   = (const float*)d_in[6];
    const float* a2   = (const float*)d_in[7];
    const float* w3   = (const float*)d_in[8];
    const float* b3   = (const float*)d_in[9];
    const float* a3   = (const float*)d_in[10];
    const float* w4   = (const float*)d_in[11];
    const float* b4   = (const float*)d_in[12];
    float* out = (float*)d_out;

    dim3 grid(2080, 1, 2);   // lower-triangle tiles only; zero tiles fused
    precond_mfma<<<grid, 256, 0, stream>>>(x, mask, w1, b1, a1, w2, b2, a2,
                                           w3, b3, a3, w4, b4, out);
}